// Round 3
// baseline (62.393 us; speedup 1.0000x reference)
//
#include <hip/hip_runtime.h>

#define BLK 256
#define NBLOCKS 3584   // 2048 (scale0) + 1024 (scale1) + 512 (scale2)

// Flat-grid scale decompose: block b ->
//   scale0: b in [0,2048)    n4=524288  sh=16
//   scale1: b in [2048,3072) n4=262144  sh=15
//   scale2: b in [3072,3584) n4=131072  sh=14
// tid = (b - base)*BLK + threadIdx.x  = float4 index within the scale.

// ---------------------------------------------------------------------------
// Distance kernel with f-reuse: load f float4 ONCE, loop all 10 items.
// Also writes the feature into CI's first half (free: f already in regs).
// Deterministic per-block partials: partials[item*NBLOCKS + b].
// ---------------------------------------------------------------------------
__global__ void dist_kernel(const float* __restrict__ f1, const float* __restrict__ M1,
                            const float* __restrict__ f2, const float* __restrict__ M2,
                            const float* __restrict__ f3, const float* __restrict__ M3,
                            float* __restrict__ out, float* __restrict__ partials) {
    const int b = blockIdx.x;
    const float* f; const float* M; int n4, sh, lb; float* CI;
    if (b < 2048)      { f = f1; M = M1; n4 = 524288; sh = 16; lb = b;        CI = out;           }
    else if (b < 3072) { f = f2; M = M2; n4 = 262144; sh = 15; lb = b - 2048; CI = out + 4194304; }
    else               { f = f3; M = M3; n4 = 131072; sh = 14; lb = b - 3072; CI = out + 6291456; }
    const int tid = lb * BLK + threadIdx.x;

    const float4* __restrict__ f4 = (const float4*)f;
    const float4* __restrict__ m4 = (const float4*)M;

    // Issue all 11 loads (1 f + 10 M) before any compute: independent VMEM.
    float4 a = f4[tid];
    float4 mv[10];
    #pragma unroll
    for (int i = 0; i < 10; ++i) mv[i] = m4[(size_t)i * n4 + tid];

    // Feature -> CI first half.
    {
        const int bi = tid >> sh, r = tid & ((1 << sh) - 1);
        ((float4*)CI)[((size_t)bi << (sh + 1)) + r] = a;
    }

    float acc[10];
    #pragma unroll
    for (int i = 0; i < 10; ++i) {
        float dx = a.x - mv[i].x, dy = a.y - mv[i].y;
        float dz = a.z - mv[i].z, dw = a.w - mv[i].w;
        acc[i] = dx * dx + dy * dy + dz * dz + dw * dw;
    }

    __shared__ float s[10][4];
    #pragma unroll
    for (int i = 0; i < 10; ++i) {
        float v = acc[i];
        #pragma unroll
        for (int off = 32; off > 0; off >>= 1) v += __shfl_down(v, off);
        if ((threadIdx.x & 63) == 0) s[i][threadIdx.x >> 6] = v;
    }
    __syncthreads();
    if (threadIdx.x < 10)
        partials[threadIdx.x * NBLOCKS + b] =
            s[threadIdx.x][0] + s[threadIdx.x][1] + s[threadIdx.x][2] + s[threadIdx.x][3];
}

// ---------------------------------------------------------------------------
// Reduce partials per (item, scale), then argmin over
// sqrt(s0)+sqrt(s1)+sqrt(s2). 1 block x 1024 threads; wave w (<10) owns
// item w and keeps the three scale ranges separate while summing.
// ---------------------------------------------------------------------------
__global__ void reduce_argmin_kernel(const float* __restrict__ partials,
                                     int* __restrict__ idx_out) {
    __shared__ float tot[10];
    const int wv = threadIdx.x >> 6, lane = threadIdx.x & 63;
    if (wv < 10) {
        const float* p = partials + wv * NBLOCKS;
        float s0 = 0.f, s1 = 0.f, s2 = 0.f;
        for (int i = lane; i < 2048; i += 64) s0 += p[i];
        for (int i = 2048 + lane; i < 3072; i += 64) s1 += p[i];
        for (int i = 3072 + lane; i < 3584; i += 64) s2 += p[i];
        #pragma unroll
        for (int off = 32; off > 0; off >>= 1) {
            s0 += __shfl_down(s0, off);
            s1 += __shfl_down(s1, off);
            s2 += __shfl_down(s2, off);
        }
        if (lane == 0) tot[wv] = sqrtf(s0) + sqrtf(s1) + sqrtf(s2);
    }
    __syncthreads();
    if (threadIdx.x == 0) {
        float best = 3.4e38f; int bi = 0;
        for (int i = 0; i < 10; ++i) {
            float t = tot[i];
            if (t < best) { best = t; bi = i; }
        }
        *idx_out = bi;
    }
}

// ---------------------------------------------------------------------------
// Gather: M[idx] float4 -> CI second half + mi. (Feature half already done.)
// ---------------------------------------------------------------------------
__global__ void gather_kernel(const float* __restrict__ M1, const float* __restrict__ M2,
                              const float* __restrict__ M3, const int* __restrict__ idx_ptr,
                              float* __restrict__ out) {
    const int b = blockIdx.x;
    const float* M; int n4, sh, lb; float* CI; float* mi;
    if (b < 2048)      { M = M1; n4 = 524288; sh = 16; lb = b;        CI = out;           mi = out + 7340032;  }
    else if (b < 3072) { M = M2; n4 = 262144; sh = 15; lb = b - 2048; CI = out + 4194304; mi = out + 9437184;  }
    else               { M = M3; n4 = 131072; sh = 14; lb = b - 3072; CI = out + 6291456; mi = out + 10485760; }
    const int tid = lb * BLK + threadIdx.x;
    const int idx = *idx_ptr;

    float4 v = ((const float4*)M)[(size_t)idx * n4 + tid];
    const int bi = tid >> sh, r = tid & ((1 << sh) - 1);
    const int S4 = 1 << sh;
    ((float4*)CI)[((size_t)bi << (sh + 1)) + S4 + r] = v;
    ((float4*)mi)[tid] = v;
}

extern "C" void kernel_launch(void* const* d_in, const int* in_sizes, int n_in,
                              void* d_out, int out_size, void* d_ws, size_t ws_size,
                              hipStream_t stream) {
    const float* f1 = (const float*)d_in[0];
    const float* f2 = (const float*)d_in[1];
    const float* f3 = (const float*)d_in[2];
    const float* M1 = (const float*)d_in[3];
    const float* M2 = (const float*)d_in[4];
    const float* M3 = (const float*)d_in[5];
    float* out = (float*)d_out;

    // Output flat layout (fp32 elements):
    //   CI1 @ 0         4194304 | CI2 @ 4194304  2097152 | CI3 @ 6291456  1048576
    //   mi1 @ 7340032   2097152 | mi2 @ 9437184  1048576 | mi3 @ 10485760  524288
    // Scratch: partials (10*NBLOCKS fp32 = 143 KB) in the mi3 region (fully
    // overwritten by gather afterwards). idx in d_ws.
    float* partials = out + 10485760;
    int* idxp = (int*)d_ws;

    dist_kernel<<<NBLOCKS, BLK, 0, stream>>>(f1, M1, f2, M2, f3, M3, out, partials);
    reduce_argmin_kernel<<<1, 1024, 0, stream>>>(partials, idxp);
    gather_kernel<<<NBLOCKS, BLK, 0, stream>>>(M1, M2, M3, idxp, out);
}